// Round 14
// baseline (212.753 us; speedup 1.0000x reference)
//
#include <hip/hip_runtime.h>
#include <stdint.h>

// DistMatchLayer via spatial bucketing, round 14.
// r13 post-mortem: fused kernel + sw grid barrier was CORRECT but the spin
// polled with atomicAdd(p,0) -- a device-scope RMW. 1023 spinners x RMW to
// one cache line serialize at the coherence point (~100us queue per
// barrier; VALUBusy 3.4%). Fix: poll with __hip_atomic_load (agent scope,
// relaxed) -- a coherent LOAD, no serialization. Arrival/release keep RMWs
// (1024 + 1 ops total, negligible). All else byte-identical to r13.
// Co-residency by construction: __launch_bounds__(512,8), VGPR=20, no LDS
// -> 4 blocks/CU x 256 CU = kBlocks=1024 (r13 proved the barrier releases).

namespace {
constexpr int kB = 4;
constexpr int kNa = 8192;
constexpr int kNb = 8192;
constexpr int kC = 64;

constexpr int kRad = 8;                 // offsets |d| <= 8, d2 <= 64
constexpr int kDMax = 64;
constexpr int kGrid = 48;               // 32 + 2*8 padded grid
constexpr int kGrid2 = kGrid * kGrid;   // 2304
constexpr int kGrid3 = kGrid2 * kGrid;  // 110592
constexpr int kOff = kRad * kGrid2 + kRad * kGrid + kRad;  // 19208

constexpr int kChunkSz = 32;
constexpr int kMaxChunks = 128;
constexpr int kTabCap = kMaxChunks * kChunkSz;   // 4096

constexpr int kOvfCap = 256;

// ws layout (u32 words)
constexpr size_t kCntOff    = 0;                                     // [442368]
constexpr size_t kOvfCntOff = 442368;                                // [4]
constexpr size_t kOvfIdxOff = 442372;                                // [1024]
constexpr size_t kSlot16Off = 443396;          // u16 slots, 2 words/cell; 16B-aligned
constexpr size_t kSlotHiOff = kSlot16Off + (size_t)kB * kGrid3 * 2;  // 1,328,132
constexpr size_t kWsWords   = kSlotHiOff + (size_t)kB * kGrid3 * 4;  // 3,097,604
constexpr size_t kWsBytes   = kWsWords * 4ull;                       // ~12.4 MB

constexpr int kZeroVecEnd = (int)((kOvfCntOff + 4) / 4);   // 110593
constexpr int kFFVecBeg   = (int)(kSlot16Off / 4);         // 110849
constexpr int kFFVecEnd   = (int)(kSlotHiOff / 4);         // 332033

constexpr int kBlocks = kB * 256;                          // 1024
constexpr int kThreads = 512;
static_assert(kFFVecEnd <= kBlocks * kThreads, "clear range must fit one pass");

struct Tab {
    uint32_t e[kTabCap];
    unsigned long long canStop[2];
    int nChunks;
};
constexpr Tab buildTab() {
    Tab t{};
    for (int i = 0; i < kTabCap; ++i) t.e[i] = 0x7FFFFFFFu;  // sentinel
    t.canStop[0] = 0; t.canStop[1] = 0;
    int cnt[kDMax + 1] = {};
    for (int dx = -kRad; dx <= kRad; ++dx)
        for (int dy = -kRad; dy <= kRad; ++dy)
            for (int dz = -kRad; dz <= kRad; ++dz) {
                const int d2 = dx * dx + dy * dy + dz * dz;
                if (d2 <= kDMax) cnt[d2]++;
            }
    int pos[kDMax + 1] = {};
    int fill = 0;
    for (int d = 0; d <= kDMax; ++d) {
        if (cnt[d] == 0) { pos[d] = -1; continue; }
        const int room = kChunkSz - (fill % kChunkSz);
        if (room < cnt[d] && room != kChunkSz) fill += room;  // shell-align
        pos[d] = fill;
        fill += cnt[d];
    }
    t.nChunks = (fill + kChunkSz - 1) / kChunkSz;
    for (int dx = -kRad; dx <= kRad; ++dx)
        for (int dy = -kRad; dy <= kRad; ++dy)
            for (int dz = -kRad; dz <= kRad; ++dz) {
                const int d2 = dx * dx + dy * dy + dz * dz;
                if (d2 <= kDMax) {
                    const int sd = dx * kGrid2 + dy * kGrid + dz + kOff;
                    t.e[pos[d2]++] = ((uint32_t)d2 << 18) | (uint32_t)sd;
                }
            }
    for (int c = 0; c < t.nChunks; ++c) {
        int lastReal = -1;
        for (int i = (c + 1) * kChunkSz - 1; i >= 0; --i) {
            const unsigned d = t.e[i] >> 18;
            if (d <= (unsigned)kDMax) { lastReal = (int)d; break; }
        }
        int nextReal = kDMax + 1;
        for (int i = (c + 1) * kChunkSz; i < kTabCap; ++i) {
            const unsigned d = t.e[i] >> 18;
            if (d <= (unsigned)kDMax) { nextReal = (int)d; break; }
        }
        if (nextReal > lastReal) t.canStop[c >> 6] |= (1ull << (c & 63));
    }
    return t;
}
__device__ constexpr Tab kTab = buildTab();          // ~16 KB .rodata
constexpr int kNChunks = buildTab().nChunks;
constexpr unsigned long long kCS0 = buildTab().canStop[0];
constexpr unsigned long long kCS1 = buildTab().canStop[1];
static_assert(buildTab().nChunks <= kMaxChunks, "table overflow");
}  // namespace

// ---- software grid barrier state (module-load zero; cnt==0 is the entry
// ---- invariant, restored by every barrier; gen is monotonic) ----
__device__ uint32_t g_barCnt;
__device__ uint32_t g_barGen;

__device__ __forceinline__ void gridBarrier() {
    __syncthreads();                       // drains this block's stores
    if (threadIdx.x == 0) {
        __threadfence();                   // agent-scope release
        const uint32_t g = __hip_atomic_load(&g_barGen, __ATOMIC_RELAXED,
                                             __HIP_MEMORY_SCOPE_AGENT);
        const uint32_t old = atomicAdd(&g_barCnt, 1u);
        if (old == (uint32_t)kBlocks - 1u) {
            atomicExch(&g_barCnt, 0u);     // reset BEFORE release
            atomicAdd(&g_barGen, 1u);
        } else {
            int bail = 0;
            // spin on a coherent LOAD (no RMW -> no serialization storm)
            while (__hip_atomic_load(&g_barGen, __ATOMIC_RELAXED,
                                     __HIP_MEMORY_SCOPE_AGENT) == g) {
                __builtin_amdgcn_s_sleep(4);
                if (++bail > 4000000) break;   // visible failure, not a hang
            }
        }
        __threadfence();                   // agent-scope acquire
    }
    __syncthreads();
}

__device__ __forceinline__ uint32_t umin_(uint32_t a, uint32_t b) { return a < b ? a : b; }
__device__ __forceinline__ uint32_t umax_(uint32_t a, uint32_t b) { return a > b ? a : b; }

#define INSERT5(T0, T1, T2, T3, T4, KEY) do {                 \
    const uint32_t m0_ = umax_(T0, KEY); T0 = umin_(T0, KEY); \
    const uint32_t m1_ = umax_(T1, m0_); T1 = umin_(T1, m0_); \
    const uint32_t m2_ = umax_(T2, m1_); T2 = umin_(T2, m1_); \
    const uint32_t m3_ = umax_(T3, m2_); T3 = umin_(T3, m2_); \
    T4 = umin_(T4, m3_); } while (0)

// unpack one u32 (2 u16 slots) and insert; sentinel 0xFFFF -> key 0xFFFFFFFF
#define UNPACK2_INS(W, KB, CNT) do {                                  \
    const uint32_t v0_ = (uint32_t)(int32_t)(int16_t)((W) & 0xFFFFu); \
    const uint32_t v1_ = (uint32_t)(int32_t)(int16_t)((W) >> 16);     \
    INSERT5(t0, t1, t2, t3, t4, (KB) | v0_);                          \
    INSERT5(t0, t1, t2, t3, t4, (KB) | v1_);                          \
    CNT += (v0_ != ~0u) + (v1_ != ~0u); } while (0)

__device__ __forceinline__ void merge5_(uint32_t& t0, uint32_t& t1, uint32_t& t2,
                                        uint32_t& t3, uint32_t& t4,
                                        uint32_t b0, uint32_t b1, uint32_t b2,
                                        uint32_t b3, uint32_t b4) {
    const uint32_t c0 = umin_(t0, b0);
    const uint32_t c1 = umin_(umin_(umax_(t0, b0), t1), b1);
    const uint32_t c2 = umin_(umin_(umax_(t0, b1), umax_(t1, b0)), umin_(t2, b2));
    const uint32_t c3 = umin_(umin_(umax_(t0, b2), umax_(t1, b1)),
                              umin_(umax_(t2, b0), umin_(t3, b3)));
    const uint32_t c4 = umin_(umin_(umax_(t0, b3), umax_(t1, b2)),
                              umin_(umin_(umax_(t2, b1), umax_(t3, b0)),
                                    umin_(t4, b4)));
    t0 = c0; t1 = c1; t2 = c2; t3 = c3; t4 = c4;
}

__device__ __forceinline__ void groupMerge5_(uint32_t& t0, uint32_t& t1, uint32_t& t2,
                                             uint32_t& t3, uint32_t& t4) {
    #pragma unroll
    for (int s = 1; s < 16; s <<= 1) {
        const uint32_t b0 = (uint32_t)__shfl_xor((int)t0, s);
        const uint32_t b1 = (uint32_t)__shfl_xor((int)t1, s);
        const uint32_t b2 = (uint32_t)__shfl_xor((int)t2, s);
        const uint32_t b3 = (uint32_t)__shfl_xor((int)t3, s);
        const uint32_t b4 = (uint32_t)__shfl_xor((int)t4, s);
        merge5_(t0, t1, t2, t3, t4, b0, b1, b2, b3, b4);
    }
}

__device__ __forceinline__ void waveMerge5_(uint32_t& t0, uint32_t& t1, uint32_t& t2,
                                            uint32_t& t3, uint32_t& t4) {
    #pragma unroll
    for (int s = 1; s < 64; s <<= 1) {
        const uint32_t b0 = (uint32_t)__shfl_xor((int)t0, s);
        const uint32_t b1 = (uint32_t)__shfl_xor((int)t1, s);
        const uint32_t b2 = (uint32_t)__shfl_xor((int)t2, s);
        const uint32_t b3 = (uint32_t)__shfl_xor((int)t3, s);
        const uint32_t b4 = (uint32_t)__shfl_xor((int)t4, s);
        merge5_(t0, t1, t2, t3, t4, b0, b1, b2, b3, b4);
    }
}

__device__ __forceinline__ int groupSum16_(int v) {
    v += __shfl_xor(v, 1);
    v += __shfl_xor(v, 2);
    v += __shfl_xor(v, 4);
    v += __shfl_xor(v, 8);
    return v;
}

// ---------------- fused kernel: clear -> scatter -> main ----------------

__global__ __launch_bounds__(kThreads, 8)
void k_fused(const int* __restrict__ coords_a,
             const int* __restrict__ coords_b,
             const float* __restrict__ feat_a,
             const float* __restrict__ feat_b,
             uint32_t* __restrict__ ws,
             float* __restrict__ out)
{
    uint32_t* cnt    = ws + kCntOff;
    uint32_t* ovfCnt = ws + kOvfCntOff;
    uint32_t* ovfIdx = ws + kOvfIdxOff;
    uint16_t* slot16 = (uint16_t*)(ws + kSlot16Off);
    uint32_t* slotHi = ws + kSlotHiOff;

    const int gtid = blockIdx.x * kThreads + threadIdx.x;

    // ---- phase 1: clear (one predicated uint4 store per thread) ----
    {
        uint4* w4 = reinterpret_cast<uint4*>(ws);
        if (gtid < kZeroVecEnd) w4[gtid] = uint4{0u, 0u, 0u, 0u};
        else if (gtid >= kFFVecBeg && gtid < kFFVecEnd)
            w4[gtid] = uint4{~0u, ~0u, ~0u, ~0u};
    }
    gridBarrier();

    // ---- phase 2: scatter (first 32K threads) ----
    if (gtid < kB * kNb) {
        const int b = gtid >> 13;
        const int j = gtid & (kNb - 1);
        const int* p = coords_b + (size_t)gtid * 3;
        const int cell = b * kGrid3
                       + (p[0] + kRad) * kGrid2 + (p[1] + kRad) * kGrid + (p[2] + kRad);
        const uint32_t pos = atomicAdd(&cnt[cell], 1u);
        if (pos < 4u) {
            slot16[(size_t)cell * 4 + pos] = (uint16_t)j;
        } else if (pos < 8u) {
            slotHi[(size_t)cell * 4 + (pos - 4u)] = (uint32_t)j;
        } else {
            const uint32_t op = atomicAdd(&ovfCnt[b], 1u);
            if (op < (uint32_t)kOvfCap) ovfIdx[b * kOvfCap + op] = (uint32_t)j;
        }
    }
    gridBarrier();

    // ---- phase 3: main (verified round-11 body) ----
    const int b = blockIdx.x >> 8;                 // 256 blocks/batch
    const int rowBase = (blockIdx.x & 255) * 32;   // 32 rows/block
    const int lane = threadIdx.x & 63;
    const int wave = threadIdx.x >> 6;
    const int sub = lane & 15;
    const int grp = lane >> 4;
    const int row = rowBase + wave * 4 + grp;

    const uint32_t ovf = ovfCnt[b];
    const size_t arow = ((size_t)b * kNa + row) * kC;
    const float4 fa = *reinterpret_cast<const float4*>(feat_a + arow + sub * 4);

    const int* ca = coords_a + ((size_t)b * kNa + row) * 3;
    const int ax = ca[0], ay = ca[1], az = ca[2];
    const int aCell = (ax + kRad) * kGrid2 + (ay + kRad) * kGrid + (az + kRad);
    const int base = b * kGrid3 + aCell - kOff;

    uint32_t t0 = 0xFFFFFFFFu, t1 = t0, t2 = t0, t3 = t0, t4 = t0;
    int myCnt = 0;

    // fused chunks 0 + 1: all 4 slot gathers in flight before inserts
    const uint2 eA = *reinterpret_cast<const uint2*>(kTab.e + sub * 2);
    const uint2 eB = *reinterpret_cast<const uint2*>(kTab.e + kChunkSz + sub * 2);
    const uint32_t dA0 = eA.x >> 18, dA1 = eA.y >> 18;
    const uint32_t dB0 = eB.x >> 18, dB1 = eB.y >> 18;
    const int cA0 = base + (int)(eA.x & 0x3FFFFu);
    const int cA1 = base + (int)(eA.y & 0x3FFFFu);
    const int cB0 = base + (int)(eB.x & 0x3FFFFu);
    const int cB1 = base + (int)(eB.y & 0x3FFFFu);
    uint2 sA0 = uint2{~0u, ~0u}, sA1 = sA0, sB0 = sA0, sB1 = sA0;
    if (dA0 <= (uint32_t)kDMax)
        sA0 = *reinterpret_cast<const uint2*>(slot16 + (size_t)cA0 * 4);
    if (dA1 <= (uint32_t)kDMax)
        sA1 = *reinterpret_cast<const uint2*>(slot16 + (size_t)cA1 * 4);
    if (dB0 <= (uint32_t)kDMax)
        sB0 = *reinterpret_cast<const uint2*>(slot16 + (size_t)cB0 * 4);
    if (dB1 <= (uint32_t)kDMax)
        sB1 = *reinterpret_cast<const uint2*>(slot16 + (size_t)cB1 * 4);

    const uint32_t kbA0 = dA0 << 13, kbA1 = dA1 << 13;
    const uint32_t kbB0 = dB0 << 13, kbB1 = dB1 << 13;

    UNPACK2_INS(sA0.x, kbA0, myCnt); UNPACK2_INS(sA0.y, kbA0, myCnt);
    UNPACK2_INS(sA1.x, kbA1, myCnt); UNPACK2_INS(sA1.y, kbA1, myCnt);
    const bool fullA0 = (sA0.y >> 16) != 0xFFFFu;
    const bool fullA1 = (sA1.y >> 16) != 0xFFFFu;
    if (__any(fullA0 | fullA1)) {
        if (fullA0) {
            const uint32_t n = umin_(cnt[cA0], 8u);
            for (uint32_t m = 4; m < n; ++m)
                INSERT5(t0, t1, t2, t3, t4, kbA0 | slotHi[(size_t)cA0 * 4 + (m - 4u)]);
        }
        if (fullA1) {
            const uint32_t n = umin_(cnt[cA1], 8u);
            for (uint32_t m = 4; m < n; ++m)
                INSERT5(t0, t1, t2, t3, t4, kbA1 | slotHi[(size_t)cA1 * 4 + (m - 4u)]);
        }
    }

    int gs = groupSum16_(myCnt);
    bool doneG = (gs >= 5);                          // chunk0 boundary is canStop

    if (__any(!doneG)) {
        if (!doneG) {
            UNPACK2_INS(sB0.x, kbB0, myCnt); UNPACK2_INS(sB0.y, kbB0, myCnt);
            UNPACK2_INS(sB1.x, kbB1, myCnt); UNPACK2_INS(sB1.y, kbB1, myCnt);
            const bool fullB0 = (sB0.y >> 16) != 0xFFFFu;
            const bool fullB1 = (sB1.y >> 16) != 0xFFFFu;
            if (__any(fullB0 | fullB1)) {
                if (fullB0) {
                    const uint32_t n = umin_(cnt[cB0], 8u);
                    for (uint32_t m = 4; m < n; ++m)
                        INSERT5(t0, t1, t2, t3, t4, kbB0 | slotHi[(size_t)cB0 * 4 + (m - 4u)]);
                }
                if (fullB1) {
                    const uint32_t n = umin_(cnt[cB1], 8u);
                    for (uint32_t m = 4; m < n; ++m)
                        INSERT5(t0, t1, t2, t3, t4, kbB1 | slotHi[(size_t)cB1 * 4 + (m - 4u)]);
                }
            }
            gs = groupSum16_(myCnt);
            doneG = (gs >= 5);
        } else {
            doneG = true;
        }
    }

    // rare continuation: sequential shell loop from c = 2
    if (__any(!doneG)) {
        bool done = doneG;
        for (int c = 2; c < kNChunks; ++c) {
            if (__all(done)) break;
            if (!done) {
                const uint2 ee = *reinterpret_cast<const uint2*>(
                                     kTab.e + c * kChunkSz + sub * 2);
                const uint32_t d20 = ee.x >> 18, d21 = ee.y >> 18;
                const int cell0 = base + (int)(ee.x & 0x3FFFFu);
                const int cell1 = base + (int)(ee.y & 0x3FFFFu);
                uint2 s0 = uint2{~0u, ~0u}, s1 = s0;
                if (d20 <= (uint32_t)kDMax)
                    s0 = *reinterpret_cast<const uint2*>(slot16 + (size_t)cell0 * 4);
                if (d21 <= (uint32_t)kDMax)
                    s1 = *reinterpret_cast<const uint2*>(slot16 + (size_t)cell1 * 4);
                const uint32_t kb0 = d20 << 13, kb1 = d21 << 13;
                UNPACK2_INS(s0.x, kb0, myCnt); UNPACK2_INS(s0.y, kb0, myCnt);
                UNPACK2_INS(s1.x, kb1, myCnt); UNPACK2_INS(s1.y, kb1, myCnt);
                const bool full0 = (s0.y >> 16) != 0xFFFFu;
                const bool full1 = (s1.y >> 16) != 0xFFFFu;
                if (__any(full0 | full1)) {
                    if (full0) {
                        const uint32_t n = umin_(cnt[cell0], 8u);
                        for (uint32_t m = 4; m < n; ++m)
                            INSERT5(t0, t1, t2, t3, t4,
                                    kb0 | slotHi[(size_t)cell0 * 4 + (m - 4u)]);
                    }
                    if (full1) {
                        const uint32_t n = umin_(cnt[cell1], 8u);
                        for (uint32_t m = 4; m < n; ++m)
                            INSERT5(t0, t1, t2, t3, t4,
                                    kb1 | slotHi[(size_t)cell1 * 4 + (m - 4u)]);
                    }
                }
                const bool canStop = (c < 64) ? (((kCS0 >> c) & 1ull) != 0)
                                              : (((kCS1 >> (c - 64)) & 1ull) != 0);
                if (canStop) {
                    if (groupSum16_(myCnt) >= 5) done = true;
                }
            }
        }
    }

    // ONE group merge per row
    groupMerge5_(t0, t1, t2, t3, t4);
    uint32_t g0 = t0, g1 = t1, g2 = t2, g3 = t3, g4 = t4;

    // overflow fold + fallback (rare/cold)
    bool needFull = (ovf > (uint32_t)kOvfCap);
    if (!needFull && ovf > 0) {
        const int* cb = coords_b + (size_t)b * kNb * 3;
        uint32_t l0 = 0xFFFFFFFFu, l1 = l0, l2 = l0, l3 = l0, l4 = l0;
        for (uint32_t i = (uint32_t)sub; i < ovf; i += 16) {
            const uint32_t j = ovfIdx[b * kOvfCap + i];
            const int dx = ax - cb[3 * j + 0];
            const int dy = ay - cb[3 * j + 1];
            const int dz = az - cb[3 * j + 2];
            const uint32_t d2 = (uint32_t)(dx * dx + dy * dy + dz * dz);
            INSERT5(l0, l1, l2, l3, l4, (d2 << 13) | j);
        }
        groupMerge5_(l0, l1, l2, l3, l4);
        merge5_(g0, g1, g2, g3, g4, l0, l1, l2, l3, l4);
    }
    if (!needFull && (g4 >> 13) > (uint32_t)kDMax) needFull = true;
    if (__any(needFull)) {
        if (needFull) {
            const int* cb = coords_b + (size_t)b * kNb * 3;
            uint32_t u0 = 0xFFFFFFFFu, u1 = u0, u2 = u0, u3 = u0, u4 = u0;
            for (int j = sub; j < kNb; j += 16) {
                const int dx = ax - cb[3 * j + 0];
                const int dy = ay - cb[3 * j + 1];
                const int dz = az - cb[3 * j + 2];
                const uint32_t d2 = (uint32_t)(dx * dx + dy * dy + dz * dz);
                INSERT5(u0, u1, u2, u3, u4, (d2 << 13) | (uint32_t)j);
            }
            groupMerge5_(u0, u1, u2, u3, u4);
            g0 = u0; g1 = u1; g2 = u2; g3 = u3; g4 = u4;
        }
    }

    // weights + gather: lane = 4 channels (float4)
    const float* fb = feat_b + (size_t)b * kNb * kC;
    const uint32_t keys[5] = {g0, g1, g2, g3, g4};
    float4 acc = float4{0.f, 0.f, 0.f, 0.f};
    #pragma unroll
    for (int t = 0; t < 5; ++t) {
        const uint32_t key = keys[t];
        const int j = (int)(key & 8191u);
        const float dist = sqrtf((float)(key >> 13)) * (1.0f / 32.0f);
        const float w = 0.5f - fminf(dist, 0.5f);
        const float4 v = *reinterpret_cast<const float4*>(
                             fb + (size_t)j * kC + sub * 4);
        acc.x += w * v.x; acc.y += w * v.y; acc.z += w * v.z; acc.w += w * v.w;
    }

    const size_t orow = ((size_t)b * kNa + row) * (2 * kC);
    *reinterpret_cast<float4*>(out + orow + sub * 4) = fa;
    *reinterpret_cast<float4*>(out + orow + kC + sub * 4) = acc;
}

// ---------------- brute kernel (fallback if ws too small) ----------------

__global__ __launch_bounds__(512, 8)
void dist_match_brute(const int* __restrict__ coords_a,
                      const int* __restrict__ coords_b,
                      const float* __restrict__ feat_a,
                      const float* __restrict__ feat_b,
                      float* __restrict__ out)
{
    __shared__ int spack[kNb];
    const int b = blockIdx.x >> 10;
    const int rowBase = (blockIdx.x & 1023) * 8;
    const int tid = threadIdx.x;
    const int lane = tid & 63;
    const int wave = tid >> 6;

    const int* cb = coords_b + (size_t)b * kNb * 3;
    for (int j = tid; j < kNb; j += 512) {
        spack[j] = cb[3 * j + 0] | (cb[3 * j + 1] << 8) | (cb[3 * j + 2] << 16);
    }
    __syncthreads();

    const int row = rowBase + wave;
    const int* ca = coords_a + ((size_t)b * kNa + row) * 3;
    const int ax = ca[0], ay = ca[1], az = ca[2];
    const int a2 = ax * ax + ay * ay + az * az;
    const int paneg2 = ((-2 * ax) & 255) | (((-2 * ay) & 255) << 8)
                     | (((-2 * az) & 255) << 16);

    uint32_t t0 = 0xFFFFFFFFu, t1 = t0, t2 = t0, t3 = t0, t4 = t0;
    for (int k = 0; k < kNb / 256; ++k) {
        const int baseI = k * 256 + lane * 4;
        const int4 p4 = *reinterpret_cast<const int4*>(spack + baseI);
        const int ps[4] = {p4.x, p4.y, p4.z, p4.w};
        #pragma unroll
        for (int u = 0; u < 4; ++u) {
            const int p = ps[u];
            const int dot1 = __builtin_amdgcn_sdot4(paneg2, p, a2, false);
            const int d2 = __builtin_amdgcn_sdot4(p, p, dot1, false);
            const uint32_t key = ((uint32_t)d2 << 13) | (uint32_t)(baseI + u);
            INSERT5(t0, t1, t2, t3, t4, key);
        }
    }
    waveMerge5_(t0, t1, t2, t3, t4);
    const float* fb = feat_b + (size_t)b * kNb * kC;
    const uint32_t keys[5] = {t0, t1, t2, t3, t4};
    float acc = 0.0f;
    #pragma unroll
    for (int t = 0; t < 5; ++t) {
        const uint32_t key = keys[t];
        const int j = (int)(key & 8191u);
        const float dist = sqrtf((float)(key >> 13)) * (1.0f / 32.0f);
        const float w = 0.5f - fminf(dist, 0.5f);
        acc += w * fb[(size_t)j * kC + lane];
    }
    const size_t orow = ((size_t)b * kNa + row) * (2 * kC);
    out[orow + lane] = feat_a[((size_t)b * kNa + row) * kC + lane];
    out[orow + kC + lane] = acc;
}

extern "C" void kernel_launch(void* const* d_in, const int* in_sizes, int n_in,
                              void* d_out, int out_size, void* d_ws, size_t ws_size,
                              hipStream_t stream) {
    const int* coords_a = (const int*)d_in[0];
    const int* coords_b = (const int*)d_in[1];
    const float* feat_a = (const float*)d_in[2];
    const float* feat_b = (const float*)d_in[3];
    float* out = (float*)d_out;

    if (ws_size < kWsBytes) {
        dist_match_brute<<<kB * 1024, 512, 0, stream>>>(coords_a, coords_b,
                                                        feat_a, feat_b, out);
        return;
    }

    k_fused<<<kBlocks, kThreads, 0, stream>>>(coords_a, coords_b,
                                              feat_a, feat_b,
                                              (uint32_t*)d_ws, out);
}

// Round 15
// 29.814 us; speedup vs baseline: 7.1361x; 7.1361x over previous
//
#include <hip/hip_runtime.h>
#include <stdint.h>

// DistMatchLayer via spatial bucketing, round 15 = round 11 (best verified,
// 30.5us) reverted after the fused-kernel arc failed: r13/r14 proved a sw
// grid barrier costs ~100us/barrier on MI355X regardless of spin flavor
// (RMW or coherent load) -- cross-XCD polling of one line serializes at the
// coherence point. 3-dispatch structure restored.
// One tweak vs r11: main kernel at 256 threads/block (2048 blocks, 16 rows
// each, 8 blocks/CU) -- same total work, finer tail granularity; scatter
// spread over 256 blocks x 128 threads so all CUs participate.
// Exact & stable (verified machinery): full keys (d2<<13)|j, shell-aligned
// count-based stop (undercount-safe), u16 sentinel slots, hi-slots via cnt
// guard, ovf fold, per-group brute fallback.

namespace {
constexpr int kB = 4;
constexpr int kNa = 8192;
constexpr int kNb = 8192;
constexpr int kC = 64;

constexpr int kRad = 8;                 // offsets |d| <= 8, d2 <= 64
constexpr int kDMax = 64;
constexpr int kGrid = 48;               // 32 + 2*8 padded grid
constexpr int kGrid2 = kGrid * kGrid;   // 2304
constexpr int kGrid3 = kGrid2 * kGrid;  // 110592
constexpr int kOff = kRad * kGrid2 + kRad * kGrid + kRad;  // 19208

constexpr int kChunkSz = 32;
constexpr int kMaxChunks = 128;
constexpr int kTabCap = kMaxChunks * kChunkSz;   // 4096

constexpr int kOvfCap = 256;

// ws layout (u32 words)
constexpr size_t kCntOff    = 0;                                     // [442368]
constexpr size_t kOvfCntOff = 442368;                                // [4]
constexpr size_t kOvfIdxOff = 442372;                                // [1024]
constexpr size_t kSlot16Off = 443396;          // u16 slots, 2 words/cell; 16B-aligned
constexpr size_t kSlotHiOff = kSlot16Off + (size_t)kB * kGrid3 * 2;  // 1,328,132
constexpr size_t kWsWords   = kSlotHiOff + (size_t)kB * kGrid3 * 4;  // 3,097,604
constexpr size_t kWsBytes   = kWsWords * 4ull;                       // ~12.4 MB

constexpr int kZeroVecEnd = (int)((kOvfCntOff + 4) / 4);   // 110593
constexpr int kFFVecBeg   = (int)(kSlot16Off / 4);         // 110849
constexpr int kFFVecEnd   = (int)(kSlotHiOff / 4);         // 332033
constexpr int kClrBlocks  = (kFFVecEnd + 255) / 256;       // 1297

struct Tab {
    uint32_t e[kTabCap];
    unsigned long long canStop[2];
    int nChunks;
};
constexpr Tab buildTab() {
    Tab t{};
    for (int i = 0; i < kTabCap; ++i) t.e[i] = 0x7FFFFFFFu;  // sentinel
    t.canStop[0] = 0; t.canStop[1] = 0;
    int cnt[kDMax + 1] = {};
    for (int dx = -kRad; dx <= kRad; ++dx)
        for (int dy = -kRad; dy <= kRad; ++dy)
            for (int dz = -kRad; dz <= kRad; ++dz) {
                const int d2 = dx * dx + dy * dy + dz * dz;
                if (d2 <= kDMax) cnt[d2]++;
            }
    int pos[kDMax + 1] = {};
    int fill = 0;
    for (int d = 0; d <= kDMax; ++d) {
        if (cnt[d] == 0) { pos[d] = -1; continue; }
        const int room = kChunkSz - (fill % kChunkSz);
        if (room < cnt[d] && room != kChunkSz) fill += room;  // shell-align
        pos[d] = fill;
        fill += cnt[d];
    }
    t.nChunks = (fill + kChunkSz - 1) / kChunkSz;
    for (int dx = -kRad; dx <= kRad; ++dx)
        for (int dy = -kRad; dy <= kRad; ++dy)
            for (int dz = -kRad; dz <= kRad; ++dz) {
                const int d2 = dx * dx + dy * dy + dz * dz;
                if (d2 <= kDMax) {
                    const int sd = dx * kGrid2 + dy * kGrid + dz + kOff;
                    t.e[pos[d2]++] = ((uint32_t)d2 << 18) | (uint32_t)sd;
                }
            }
    for (int c = 0; c < t.nChunks; ++c) {
        int lastReal = -1;
        for (int i = (c + 1) * kChunkSz - 1; i >= 0; --i) {
            const unsigned d = t.e[i] >> 18;
            if (d <= (unsigned)kDMax) { lastReal = (int)d; break; }
        }
        int nextReal = kDMax + 1;
        for (int i = (c + 1) * kChunkSz; i < kTabCap; ++i) {
            const unsigned d = t.e[i] >> 18;
            if (d <= (unsigned)kDMax) { nextReal = (int)d; break; }
        }
        if (nextReal > lastReal) t.canStop[c >> 6] |= (1ull << (c & 63));
    }
    return t;
}
__device__ constexpr Tab kTab = buildTab();          // ~16 KB .rodata
constexpr int kNChunks = buildTab().nChunks;
constexpr unsigned long long kCS0 = buildTab().canStop[0];
constexpr unsigned long long kCS1 = buildTab().canStop[1];
static_assert(buildTab().nChunks <= kMaxChunks, "table overflow");
}  // namespace

__device__ __forceinline__ uint32_t umin_(uint32_t a, uint32_t b) { return a < b ? a : b; }
__device__ __forceinline__ uint32_t umax_(uint32_t a, uint32_t b) { return a > b ? a : b; }

#define INSERT5(T0, T1, T2, T3, T4, KEY) do {                 \
    const uint32_t m0_ = umax_(T0, KEY); T0 = umin_(T0, KEY); \
    const uint32_t m1_ = umax_(T1, m0_); T1 = umin_(T1, m0_); \
    const uint32_t m2_ = umax_(T2, m1_); T2 = umin_(T2, m1_); \
    const uint32_t m3_ = umax_(T3, m2_); T3 = umin_(T3, m2_); \
    T4 = umin_(T4, m3_); } while (0)

// unpack one u32 (2 u16 slots) and insert; sentinel 0xFFFF -> key 0xFFFFFFFF
#define UNPACK2_INS(W, KB, CNT) do {                                  \
    const uint32_t v0_ = (uint32_t)(int32_t)(int16_t)((W) & 0xFFFFu); \
    const uint32_t v1_ = (uint32_t)(int32_t)(int16_t)((W) >> 16);     \
    INSERT5(t0, t1, t2, t3, t4, (KB) | v0_);                          \
    INSERT5(t0, t1, t2, t3, t4, (KB) | v1_);                          \
    CNT += (v0_ != ~0u) + (v1_ != ~0u); } while (0)

__device__ __forceinline__ void merge5_(uint32_t& t0, uint32_t& t1, uint32_t& t2,
                                        uint32_t& t3, uint32_t& t4,
                                        uint32_t b0, uint32_t b1, uint32_t b2,
                                        uint32_t b3, uint32_t b4) {
    const uint32_t c0 = umin_(t0, b0);
    const uint32_t c1 = umin_(umin_(umax_(t0, b0), t1), b1);
    const uint32_t c2 = umin_(umin_(umax_(t0, b1), umax_(t1, b0)), umin_(t2, b2));
    const uint32_t c3 = umin_(umin_(umax_(t0, b2), umax_(t1, b1)),
                              umin_(umax_(t2, b0), umin_(t3, b3)));
    const uint32_t c4 = umin_(umin_(umax_(t0, b3), umax_(t1, b2)),
                              umin_(umin_(umax_(t2, b1), umax_(t3, b0)),
                                    umin_(t4, b4)));
    t0 = c0; t1 = c1; t2 = c2; t3 = c3; t4 = c4;
}

__device__ __forceinline__ void groupMerge5_(uint32_t& t0, uint32_t& t1, uint32_t& t2,
                                             uint32_t& t3, uint32_t& t4) {
    #pragma unroll
    for (int s = 1; s < 16; s <<= 1) {
        const uint32_t b0 = (uint32_t)__shfl_xor((int)t0, s);
        const uint32_t b1 = (uint32_t)__shfl_xor((int)t1, s);
        const uint32_t b2 = (uint32_t)__shfl_xor((int)t2, s);
        const uint32_t b3 = (uint32_t)__shfl_xor((int)t3, s);
        const uint32_t b4 = (uint32_t)__shfl_xor((int)t4, s);
        merge5_(t0, t1, t2, t3, t4, b0, b1, b2, b3, b4);
    }
}

__device__ __forceinline__ void waveMerge5_(uint32_t& t0, uint32_t& t1, uint32_t& t2,
                                            uint32_t& t3, uint32_t& t4) {
    #pragma unroll
    for (int s = 1; s < 64; s <<= 1) {
        const uint32_t b0 = (uint32_t)__shfl_xor((int)t0, s);
        const uint32_t b1 = (uint32_t)__shfl_xor((int)t1, s);
        const uint32_t b2 = (uint32_t)__shfl_xor((int)t2, s);
        const uint32_t b3 = (uint32_t)__shfl_xor((int)t3, s);
        const uint32_t b4 = (uint32_t)__shfl_xor((int)t4, s);
        merge5_(t0, t1, t2, t3, t4, b0, b1, b2, b3, b4);
    }
}

__device__ __forceinline__ int groupSum16_(int v) {
    v += __shfl_xor(v, 1);
    v += __shfl_xor(v, 2);
    v += __shfl_xor(v, 4);
    v += __shfl_xor(v, 8);
    return v;
}

// ---------------- clear + scatter ----------------

__global__ __launch_bounds__(256)
void k_clear(uint4* __restrict__ ws) {
    const int i = blockIdx.x * 256 + threadIdx.x;
    if (i < kZeroVecEnd) ws[i] = uint4{0u, 0u, 0u, 0u};
    else if (i >= kFFVecBeg && i < kFFVecEnd) ws[i] = uint4{~0u, ~0u, ~0u, ~0u};
}

__global__ __launch_bounds__(128)
void k_scatter(const int* __restrict__ coords_b,
               uint32_t* __restrict__ cnt,
               uint16_t* __restrict__ slot16,
               uint32_t* __restrict__ slotHi,
               uint32_t* __restrict__ ovfCnt,
               uint32_t* __restrict__ ovfIdx) {
    const int i = blockIdx.x * blockDim.x + threadIdx.x;
    if (i >= kB * kNb) return;
    const int b = i >> 13;
    const int j = i & (kNb - 1);
    const int* p = coords_b + (size_t)i * 3;
    const int cell = b * kGrid3
                   + (p[0] + kRad) * kGrid2 + (p[1] + kRad) * kGrid + (p[2] + kRad);
    const uint32_t pos = atomicAdd(&cnt[cell], 1u);
    if (pos < 4u) {
        slot16[(size_t)cell * 4 + pos] = (uint16_t)j;   // byte-enable store, race-free
    } else if (pos < 8u) {
        slotHi[(size_t)cell * 4 + (pos - 4u)] = (uint32_t)j;
    } else {
        const uint32_t op = atomicAdd(&ovfCnt[b], 1u);
        if (op < (uint32_t)kOvfCap) ovfIdx[b * kOvfCap + op] = (uint32_t)j;
    }
}

// ---------------- main kernel: 16-lane group per row ----------------
// 256 threads/block, 16 rows/block, 2048 blocks (8 blocks/CU co-resident)

__global__ __launch_bounds__(256, 8)
void dist_match_bucket(const int* __restrict__ coords_a,
                       const int* __restrict__ coords_b,
                       const float* __restrict__ feat_a,
                       const float* __restrict__ feat_b,
                       const uint32_t* __restrict__ cnt,
                       const uint16_t* __restrict__ slot16,
                       const uint32_t* __restrict__ slotHi,
                       const uint32_t* __restrict__ ovfCnt,
                       const uint32_t* __restrict__ ovfIdx,
                       float* __restrict__ out)
{
    const int b = blockIdx.x >> 9;                 // 512 blocks/batch
    const int rowBase = (blockIdx.x & 511) * 16;   // 16 rows/block
    const int lane = threadIdx.x & 63;
    const int wave = threadIdx.x >> 6;             // 0..3
    const int sub = lane & 15;
    const int grp = lane >> 4;
    const int row = rowBase + wave * 4 + grp;

    // early independent loads (overlap the search)
    const uint32_t ovf = ovfCnt[b];
    const size_t arow = ((size_t)b * kNa + row) * kC;
    const float4 fa = *reinterpret_cast<const float4*>(feat_a + arow + sub * 4);

    const int* ca = coords_a + ((size_t)b * kNa + row) * 3;
    const int ax = ca[0], ay = ca[1], az = ca[2];
    const int aCell = (ax + kRad) * kGrid2 + (ay + kRad) * kGrid + (az + kRad);
    const int base = b * kGrid3 + aCell - kOff;

    uint32_t t0 = 0xFFFFFFFFu, t1 = t0, t2 = t0, t3 = t0, t4 = t0;
    int myCnt = 0;

    // ---- fused chunks 0 + 1: all 4 slot gathers in flight before inserts ----
    const uint2 eA = *reinterpret_cast<const uint2*>(kTab.e + sub * 2);
    const uint2 eB = *reinterpret_cast<const uint2*>(kTab.e + kChunkSz + sub * 2);
    const uint32_t dA0 = eA.x >> 18, dA1 = eA.y >> 18;
    const uint32_t dB0 = eB.x >> 18, dB1 = eB.y >> 18;
    const int cA0 = base + (int)(eA.x & 0x3FFFFu);
    const int cA1 = base + (int)(eA.y & 0x3FFFFu);
    const int cB0 = base + (int)(eB.x & 0x3FFFFu);
    const int cB1 = base + (int)(eB.y & 0x3FFFFu);
    uint2 sA0 = uint2{~0u, ~0u}, sA1 = sA0, sB0 = sA0, sB1 = sA0;
    if (dA0 <= (uint32_t)kDMax)
        sA0 = *reinterpret_cast<const uint2*>(slot16 + (size_t)cA0 * 4);
    if (dA1 <= (uint32_t)kDMax)
        sA1 = *reinterpret_cast<const uint2*>(slot16 + (size_t)cA1 * 4);
    if (dB0 <= (uint32_t)kDMax)
        sB0 = *reinterpret_cast<const uint2*>(slot16 + (size_t)cB0 * 4);
    if (dB1 <= (uint32_t)kDMax)
        sB1 = *reinterpret_cast<const uint2*>(slot16 + (size_t)cB1 * 4);

    const uint32_t kbA0 = dA0 << 13, kbA1 = dA1 << 13;
    const uint32_t kbB0 = dB0 << 13, kbB1 = dB1 << 13;

    // chunk 0 inserts
    UNPACK2_INS(sA0.x, kbA0, myCnt); UNPACK2_INS(sA0.y, kbA0, myCnt);
    UNPACK2_INS(sA1.x, kbA1, myCnt); UNPACK2_INS(sA1.y, kbA1, myCnt);
    const bool fullA0 = (sA0.y >> 16) != 0xFFFFu;   // slot3 valid => maybe >4 pts
    const bool fullA1 = (sA1.y >> 16) != 0xFFFFu;
    if (__any(fullA0 | fullA1)) {
        if (fullA0) {
            const uint32_t n = umin_(cnt[cA0], 8u);
            for (uint32_t m = 4; m < n; ++m)
                INSERT5(t0, t1, t2, t3, t4, kbA0 | slotHi[(size_t)cA0 * 4 + (m - 4u)]);
        }
        if (fullA1) {
            const uint32_t n = umin_(cnt[cA1], 8u);
            for (uint32_t m = 4; m < n; ++m)
                INSERT5(t0, t1, t2, t3, t4, kbA1 | slotHi[(size_t)cA1 * 4 + (m - 4u)]);
        }
    }

    int gs = groupSum16_(myCnt);
    bool doneG = (gs >= 5);                          // chunk0 boundary is canStop

    // chunk 1 inserts (data already fetched; skip if group satisfied)
    if (__any(!doneG)) {
        if (!doneG) {
            UNPACK2_INS(sB0.x, kbB0, myCnt); UNPACK2_INS(sB0.y, kbB0, myCnt);
            UNPACK2_INS(sB1.x, kbB1, myCnt); UNPACK2_INS(sB1.y, kbB1, myCnt);
            const bool fullB0 = (sB0.y >> 16) != 0xFFFFu;
            const bool fullB1 = (sB1.y >> 16) != 0xFFFFu;
            if (__any(fullB0 | fullB1)) {
                if (fullB0) {
                    const uint32_t n = umin_(cnt[cB0], 8u);
                    for (uint32_t m = 4; m < n; ++m)
                        INSERT5(t0, t1, t2, t3, t4, kbB0 | slotHi[(size_t)cB0 * 4 + (m - 4u)]);
                }
                if (fullB1) {
                    const uint32_t n = umin_(cnt[cB1], 8u);
                    for (uint32_t m = 4; m < n; ++m)
                        INSERT5(t0, t1, t2, t3, t4, kbB1 | slotHi[(size_t)cB1 * 4 + (m - 4u)]);
                }
            }
            gs = groupSum16_(myCnt);
            doneG = (gs >= 5);                       // chunk1 boundary is canStop
        } else {
            doneG = true;
        }
    }

    // ---- rare continuation: sequential shell loop from c = 2 ----
    if (__any(!doneG)) {
        bool done = doneG;
        for (int c = 2; c < kNChunks; ++c) {
            if (__all(done)) break;
            if (!done) {
                const uint2 ee = *reinterpret_cast<const uint2*>(
                                     kTab.e + c * kChunkSz + sub * 2);
                const uint32_t d20 = ee.x >> 18, d21 = ee.y >> 18;
                const int cell0 = base + (int)(ee.x & 0x3FFFFu);
                const int cell1 = base + (int)(ee.y & 0x3FFFFu);
                uint2 s0 = uint2{~0u, ~0u}, s1 = s0;
                if (d20 <= (uint32_t)kDMax)
                    s0 = *reinterpret_cast<const uint2*>(slot16 + (size_t)cell0 * 4);
                if (d21 <= (uint32_t)kDMax)
                    s1 = *reinterpret_cast<const uint2*>(slot16 + (size_t)cell1 * 4);
                const uint32_t kb0 = d20 << 13, kb1 = d21 << 13;
                UNPACK2_INS(s0.x, kb0, myCnt); UNPACK2_INS(s0.y, kb0, myCnt);
                UNPACK2_INS(s1.x, kb1, myCnt); UNPACK2_INS(s1.y, kb1, myCnt);
                const bool full0 = (s0.y >> 16) != 0xFFFFu;
                const bool full1 = (s1.y >> 16) != 0xFFFFu;
                if (__any(full0 | full1)) {
                    if (full0) {
                        const uint32_t n = umin_(cnt[cell0], 8u);
                        for (uint32_t m = 4; m < n; ++m)
                            INSERT5(t0, t1, t2, t3, t4,
                                    kb0 | slotHi[(size_t)cell0 * 4 + (m - 4u)]);
                    }
                    if (full1) {
                        const uint32_t n = umin_(cnt[cell1], 8u);
                        for (uint32_t m = 4; m < n; ++m)
                            INSERT5(t0, t1, t2, t3, t4,
                                    kb1 | slotHi[(size_t)cell1 * 4 + (m - 4u)]);
                    }
                }
                const bool canStop = (c < 64) ? (((kCS0 >> c) & 1ull) != 0)
                                              : (((kCS1 >> (c - 64)) & 1ull) != 0);
                if (canStop) {
                    if (groupSum16_(myCnt) >= 5) done = true;
                }
            }
        }
    }

    // ONE group merge per row
    groupMerge5_(t0, t1, t2, t3, t4);
    uint32_t g0 = t0, g1 = t1, g2 = t2, g3 = t3, g4 = t4;

    // ---- overflow fold + fallback (rare/cold) ----
    bool needFull = (ovf > (uint32_t)kOvfCap);
    if (!needFull && ovf > 0) {
        const int* cb = coords_b + (size_t)b * kNb * 3;
        uint32_t l0 = 0xFFFFFFFFu, l1 = l0, l2 = l0, l3 = l0, l4 = l0;
        for (uint32_t i = (uint32_t)sub; i < ovf; i += 16) {
            const uint32_t j = ovfIdx[b * kOvfCap + i];
            const int dx = ax - cb[3 * j + 0];
            const int dy = ay - cb[3 * j + 1];
            const int dz = az - cb[3 * j + 2];
            const uint32_t d2 = (uint32_t)(dx * dx + dy * dy + dz * dz);
            INSERT5(l0, l1, l2, l3, l4, (d2 << 13) | j);
        }
        groupMerge5_(l0, l1, l2, l3, l4);
        merge5_(g0, g1, g2, g3, g4, l0, l1, l2, l3, l4);
    }
    if (!needFull && (g4 >> 13) > (uint32_t)kDMax) needFull = true;
    if (__any(needFull)) {
        if (needFull) {                            // group-uniform predicate
            const int* cb = coords_b + (size_t)b * kNb * 3;
            uint32_t u0 = 0xFFFFFFFFu, u1 = u0, u2 = u0, u3 = u0, u4 = u0;
            for (int j = sub; j < kNb; j += 16) {
                const int dx = ax - cb[3 * j + 0];
                const int dy = ay - cb[3 * j + 1];
                const int dz = az - cb[3 * j + 2];
                const uint32_t d2 = (uint32_t)(dx * dx + dy * dy + dz * dz);
                INSERT5(u0, u1, u2, u3, u4, (d2 << 13) | (uint32_t)j);
            }
            groupMerge5_(u0, u1, u2, u3, u4);
            g0 = u0; g1 = u1; g2 = u2; g3 = u3; g4 = u4;
        }
    }

    // ---- weights + gather: lane = 4 channels (float4) ----
    const float* fb = feat_b + (size_t)b * kNb * kC;
    const uint32_t keys[5] = {g0, g1, g2, g3, g4};
    float4 acc = float4{0.f, 0.f, 0.f, 0.f};
    #pragma unroll
    for (int t = 0; t < 5; ++t) {
        const uint32_t key = keys[t];
        const int j = (int)(key & 8191u);
        const float dist = sqrtf((float)(key >> 13)) * (1.0f / 32.0f);
        const float w = 0.5f - fminf(dist, 0.5f);
        const float4 v = *reinterpret_cast<const float4*>(
                             fb + (size_t)j * kC + sub * 4);
        acc.x += w * v.x; acc.y += w * v.y; acc.z += w * v.z; acc.w += w * v.w;
    }

    const size_t orow = ((size_t)b * kNa + row) * (2 * kC);
    *reinterpret_cast<float4*>(out + orow + sub * 4) = fa;
    *reinterpret_cast<float4*>(out + orow + kC + sub * 4) = acc;
}

// ---------------- brute kernel (fallback if ws too small) ----------------

__global__ __launch_bounds__(512, 8)
void dist_match_brute(const int* __restrict__ coords_a,
                      const int* __restrict__ coords_b,
                      const float* __restrict__ feat_a,
                      const float* __restrict__ feat_b,
                      float* __restrict__ out)
{
    __shared__ int spack[kNb];
    const int b = blockIdx.x >> 10;
    const int rowBase = (blockIdx.x & 1023) * 8;
    const int tid = threadIdx.x;
    const int lane = tid & 63;
    const int wave = tid >> 6;

    const int* cb = coords_b + (size_t)b * kNb * 3;
    for (int j = tid; j < kNb; j += 512) {
        spack[j] = cb[3 * j + 0] | (cb[3 * j + 1] << 8) | (cb[3 * j + 2] << 16);
    }
    __syncthreads();

    const int row = rowBase + wave;
    const int* ca = coords_a + ((size_t)b * kNa + row) * 3;
    const int ax = ca[0], ay = ca[1], az = ca[2];
    const int a2 = ax * ax + ay * ay + az * az;
    const int paneg2 = ((-2 * ax) & 255) | (((-2 * ay) & 255) << 8)
                     | (((-2 * az) & 255) << 16);

    uint32_t t0 = 0xFFFFFFFFu, t1 = t0, t2 = t0, t3 = t0, t4 = t0;
    for (int k = 0; k < kNb / 256; ++k) {
        const int baseI = k * 256 + lane * 4;
        const int4 p4 = *reinterpret_cast<const int4*>(spack + baseI);
        const int ps[4] = {p4.x, p4.y, p4.z, p4.w};
        #pragma unroll
        for (int u = 0; u < 4; ++u) {
            const int p = ps[u];
            const int dot1 = __builtin_amdgcn_sdot4(paneg2, p, a2, false);
            const int d2 = __builtin_amdgcn_sdot4(p, p, dot1, false);
            const uint32_t key = ((uint32_t)d2 << 13) | (uint32_t)(baseI + u);
            INSERT5(t0, t1, t2, t3, t4, key);
        }
    }
    waveMerge5_(t0, t1, t2, t3, t4);
    const float* fb = feat_b + (size_t)b * kNb * kC;
    const uint32_t keys[5] = {t0, t1, t2, t3, t4};
    float acc = 0.0f;
    #pragma unroll
    for (int t = 0; t < 5; ++t) {
        const uint32_t key = keys[t];
        const int j = (int)(key & 8191u);
        const float dist = sqrtf((float)(key >> 13)) * (1.0f / 32.0f);
        const float w = 0.5f - fminf(dist, 0.5f);
        acc += w * fb[(size_t)j * kC + lane];
    }
    const size_t orow = ((size_t)b * kNa + row) * (2 * kC);
    out[orow + lane] = feat_a[((size_t)b * kNa + row) * kC + lane];
    out[orow + kC + lane] = acc;
}

extern "C" void kernel_launch(void* const* d_in, const int* in_sizes, int n_in,
                              void* d_out, int out_size, void* d_ws, size_t ws_size,
                              hipStream_t stream) {
    const int* coords_a = (const int*)d_in[0];
    const int* coords_b = (const int*)d_in[1];
    const float* feat_a = (const float*)d_in[2];
    const float* feat_b = (const float*)d_in[3];
    float* out = (float*)d_out;

    if (ws_size < kWsBytes) {
        dist_match_brute<<<kB * 1024, 512, 0, stream>>>(coords_a, coords_b,
                                                        feat_a, feat_b, out);
        return;
    }

    uint32_t* ws32 = (uint32_t*)d_ws;
    uint32_t* cnt    = ws32 + kCntOff;
    uint32_t* ovfCnt = ws32 + kOvfCntOff;
    uint32_t* ovfIdx = ws32 + kOvfIdxOff;
    uint16_t* slot16 = (uint16_t*)(ws32 + kSlot16Off);
    uint32_t* slotHi = ws32 + kSlotHiOff;

    k_clear<<<kClrBlocks, 256, 0, stream>>>((uint4*)d_ws);
    k_scatter<<<kB * kNb / 128, 128, 0, stream>>>(coords_b, cnt, slot16, slotHi,
                                                  ovfCnt, ovfIdx);
    dist_match_bucket<<<kB * 512, 256, 0, stream>>>(coords_a, coords_b,
                                                    feat_a, feat_b,
                                                    cnt, slot16, slotHi,
                                                    ovfCnt, ovfIdx, out);
}

// Round 16
// 29.442 us; speedup vs baseline: 7.2261x; 1.0126x over previous
//
#include <hip/hip_runtime.h>
#include <stdint.h>

// DistMatchLayer via spatial bucketing, round 16 = round 15 with the search
// radius tightened: kRad 8->5 (d2<=25). Ball(5) ~= 515 cells x lambda 0.25 =
// ~129 expected points; P(<5 points within d<=5) < 1e-40, and the needFull
// full-rescan keeps even that case EXACT. Shrinks clear bytes 7.1->3.6 MB
// and fits the hot slot16/cnt arrays well within per-XCD L2.
// All verified machinery unchanged (parametric in kRad/kDMax/kGrid): full
// keys (d2<<13)|j, shell-aligned count-stop (undercount-safe), u16 sentinel
// slots, hi-slots via cnt guard, ovf fold, per-group brute fallback.

namespace {
constexpr int kB = 4;
constexpr int kNa = 8192;
constexpr int kNb = 8192;
constexpr int kC = 64;

constexpr int kRad = 5;                 // offsets |d| <= 5, d2 <= 25
constexpr int kDMax = 25;
constexpr int kGrid = 42;               // 32 + 2*5 padded grid
constexpr int kGrid2 = kGrid * kGrid;   // 1764
constexpr int kGrid3 = kGrid2 * kGrid;  // 74088
constexpr int kOff = kRad * kGrid2 + kRad * kGrid + kRad;  // 9035

constexpr int kChunkSz = 32;
constexpr int kMaxChunks = 128;
constexpr int kTabCap = kMaxChunks * kChunkSz;   // 4096

constexpr int kOvfCap = 256;

// ws layout (u32 words)
constexpr size_t kCntOff    = 0;                                     // [296352]
constexpr size_t kOvfCntOff = (size_t)kB * kGrid3;                   // 296352 [4]
constexpr size_t kOvfIdxOff = kOvfCntOff + 4;                        // [1024]
constexpr size_t kSlot16Off = kOvfIdxOff + kB * kOvfCap;             // 297380 (16B-aligned)
constexpr size_t kSlotHiOff = kSlot16Off + (size_t)kB * kGrid3 * 2;  // 890084
constexpr size_t kWsWords   = kSlotHiOff + (size_t)kB * kGrid3 * 4;  // 2075492
constexpr size_t kWsBytes   = kWsWords * 4ull;                       // ~8.3 MB
static_assert(kSlot16Off % 4 == 0, "slot16 must be 16B aligned");

constexpr int kZeroVecEnd = (int)((kOvfCntOff + 4) / 4);   // 74089
constexpr int kFFVecBeg   = (int)(kSlot16Off / 4);         // 74345
constexpr int kFFVecEnd   = (int)(kSlotHiOff / 4);         // 222521
constexpr int kClrBlocks  = (kFFVecEnd + 255) / 256;       // 870

struct Tab {
    uint32_t e[kTabCap];
    unsigned long long canStop[2];
    int nChunks;
};
constexpr Tab buildTab() {
    Tab t{};
    for (int i = 0; i < kTabCap; ++i) t.e[i] = 0x7FFFFFFFu;  // sentinel
    t.canStop[0] = 0; t.canStop[1] = 0;
    int cnt[kDMax + 1] = {};
    for (int dx = -kRad; dx <= kRad; ++dx)
        for (int dy = -kRad; dy <= kRad; ++dy)
            for (int dz = -kRad; dz <= kRad; ++dz) {
                const int d2 = dx * dx + dy * dy + dz * dz;
                if (d2 <= kDMax) cnt[d2]++;
            }
    int pos[kDMax + 1] = {};
    int fill = 0;
    for (int d = 0; d <= kDMax; ++d) {
        if (cnt[d] == 0) { pos[d] = -1; continue; }
        const int room = kChunkSz - (fill % kChunkSz);
        if (room < cnt[d] && room != kChunkSz) fill += room;  // shell-align
        pos[d] = fill;
        fill += cnt[d];
    }
    t.nChunks = (fill + kChunkSz - 1) / kChunkSz;
    for (int dx = -kRad; dx <= kRad; ++dx)
        for (int dy = -kRad; dy <= kRad; ++dy)
            for (int dz = -kRad; dz <= kRad; ++dz) {
                const int d2 = dx * dx + dy * dy + dz * dz;
                if (d2 <= kDMax) {
                    const int sd = dx * kGrid2 + dy * kGrid + dz + kOff;
                    t.e[pos[d2]++] = ((uint32_t)d2 << 18) | (uint32_t)sd;
                }
            }
    for (int c = 0; c < t.nChunks; ++c) {
        int lastReal = -1;
        for (int i = (c + 1) * kChunkSz - 1; i >= 0; --i) {
            const unsigned d = t.e[i] >> 18;
            if (d <= (unsigned)kDMax) { lastReal = (int)d; break; }
        }
        int nextReal = kDMax + 1;
        for (int i = (c + 1) * kChunkSz; i < kTabCap; ++i) {
            const unsigned d = t.e[i] >> 18;
            if (d <= (unsigned)kDMax) { nextReal = (int)d; break; }
        }
        if (nextReal > lastReal) t.canStop[c >> 6] |= (1ull << (c & 63));
    }
    return t;
}
__device__ constexpr Tab kTab = buildTab();          // ~16 KB .rodata
constexpr int kNChunks = buildTab().nChunks;
constexpr unsigned long long kCS0 = buildTab().canStop[0];
constexpr unsigned long long kCS1 = buildTab().canStop[1];
static_assert(buildTab().nChunks <= kMaxChunks, "table overflow");
}  // namespace

__device__ __forceinline__ uint32_t umin_(uint32_t a, uint32_t b) { return a < b ? a : b; }
__device__ __forceinline__ uint32_t umax_(uint32_t a, uint32_t b) { return a > b ? a : b; }

#define INSERT5(T0, T1, T2, T3, T4, KEY) do {                 \
    const uint32_t m0_ = umax_(T0, KEY); T0 = umin_(T0, KEY); \
    const uint32_t m1_ = umax_(T1, m0_); T1 = umin_(T1, m0_); \
    const uint32_t m2_ = umax_(T2, m1_); T2 = umin_(T2, m1_); \
    const uint32_t m3_ = umax_(T3, m2_); T3 = umin_(T3, m2_); \
    T4 = umin_(T4, m3_); } while (0)

// unpack one u32 (2 u16 slots) and insert; sentinel 0xFFFF -> key 0xFFFFFFFF
#define UNPACK2_INS(W, KB, CNT) do {                                  \
    const uint32_t v0_ = (uint32_t)(int32_t)(int16_t)((W) & 0xFFFFu); \
    const uint32_t v1_ = (uint32_t)(int32_t)(int16_t)((W) >> 16);     \
    INSERT5(t0, t1, t2, t3, t4, (KB) | v0_);                          \
    INSERT5(t0, t1, t2, t3, t4, (KB) | v1_);                          \
    CNT += (v0_ != ~0u) + (v1_ != ~0u); } while (0)

__device__ __forceinline__ void merge5_(uint32_t& t0, uint32_t& t1, uint32_t& t2,
                                        uint32_t& t3, uint32_t& t4,
                                        uint32_t b0, uint32_t b1, uint32_t b2,
                                        uint32_t b3, uint32_t b4) {
    const uint32_t c0 = umin_(t0, b0);
    const uint32_t c1 = umin_(umin_(umax_(t0, b0), t1), b1);
    const uint32_t c2 = umin_(umin_(umax_(t0, b1), umax_(t1, b0)), umin_(t2, b2));
    const uint32_t c3 = umin_(umin_(umax_(t0, b2), umax_(t1, b1)),
                              umin_(umax_(t2, b0), umin_(t3, b3)));
    const uint32_t c4 = umin_(umin_(umax_(t0, b3), umax_(t1, b2)),
                              umin_(umin_(umax_(t2, b1), umax_(t3, b0)),
                                    umin_(t4, b4)));
    t0 = c0; t1 = c1; t2 = c2; t3 = c3; t4 = c4;
}

__device__ __forceinline__ void groupMerge5_(uint32_t& t0, uint32_t& t1, uint32_t& t2,
                                             uint32_t& t3, uint32_t& t4) {
    #pragma unroll
    for (int s = 1; s < 16; s <<= 1) {
        const uint32_t b0 = (uint32_t)__shfl_xor((int)t0, s);
        const uint32_t b1 = (uint32_t)__shfl_xor((int)t1, s);
        const uint32_t b2 = (uint32_t)__shfl_xor((int)t2, s);
        const uint32_t b3 = (uint32_t)__shfl_xor((int)t3, s);
        const uint32_t b4 = (uint32_t)__shfl_xor((int)t4, s);
        merge5_(t0, t1, t2, t3, t4, b0, b1, b2, b3, b4);
    }
}

__device__ __forceinline__ void waveMerge5_(uint32_t& t0, uint32_t& t1, uint32_t& t2,
                                            uint32_t& t3, uint32_t& t4) {
    #pragma unroll
    for (int s = 1; s < 64; s <<= 1) {
        const uint32_t b0 = (uint32_t)__shfl_xor((int)t0, s);
        const uint32_t b1 = (uint32_t)__shfl_xor((int)t1, s);
        const uint32_t b2 = (uint32_t)__shfl_xor((int)t2, s);
        const uint32_t b3 = (uint32_t)__shfl_xor((int)t3, s);
        const uint32_t b4 = (uint32_t)__shfl_xor((int)t4, s);
        merge5_(t0, t1, t2, t3, t4, b0, b1, b2, b3, b4);
    }
}

__device__ __forceinline__ int groupSum16_(int v) {
    v += __shfl_xor(v, 1);
    v += __shfl_xor(v, 2);
    v += __shfl_xor(v, 4);
    v += __shfl_xor(v, 8);
    return v;
}

// ---------------- clear + scatter ----------------

__global__ __launch_bounds__(256)
void k_clear(uint4* __restrict__ ws) {
    const int i = blockIdx.x * 256 + threadIdx.x;
    if (i < kZeroVecEnd) ws[i] = uint4{0u, 0u, 0u, 0u};
    else if (i >= kFFVecBeg && i < kFFVecEnd) ws[i] = uint4{~0u, ~0u, ~0u, ~0u};
}

__global__ __launch_bounds__(128)
void k_scatter(const int* __restrict__ coords_b,
               uint32_t* __restrict__ cnt,
               uint16_t* __restrict__ slot16,
               uint32_t* __restrict__ slotHi,
               uint32_t* __restrict__ ovfCnt,
               uint32_t* __restrict__ ovfIdx) {
    const int i = blockIdx.x * blockDim.x + threadIdx.x;
    if (i >= kB * kNb) return;
    const int b = i >> 13;
    const int j = i & (kNb - 1);
    const int* p = coords_b + (size_t)i * 3;
    const int cell = b * kGrid3
                   + (p[0] + kRad) * kGrid2 + (p[1] + kRad) * kGrid + (p[2] + kRad);
    const uint32_t pos = atomicAdd(&cnt[cell], 1u);
    if (pos < 4u) {
        slot16[(size_t)cell * 4 + pos] = (uint16_t)j;   // byte-enable store, race-free
    } else if (pos < 8u) {
        slotHi[(size_t)cell * 4 + (pos - 4u)] = (uint32_t)j;
    } else {
        const uint32_t op = atomicAdd(&ovfCnt[b], 1u);
        if (op < (uint32_t)kOvfCap) ovfIdx[b * kOvfCap + op] = (uint32_t)j;
    }
}

// ---------------- main kernel: 16-lane group per row ----------------
// 256 threads/block, 16 rows/block, 2048 blocks (8 blocks/CU co-resident)

__global__ __launch_bounds__(256, 8)
void dist_match_bucket(const int* __restrict__ coords_a,
                       const int* __restrict__ coords_b,
                       const float* __restrict__ feat_a,
                       const float* __restrict__ feat_b,
                       const uint32_t* __restrict__ cnt,
                       const uint16_t* __restrict__ slot16,
                       const uint32_t* __restrict__ slotHi,
                       const uint32_t* __restrict__ ovfCnt,
                       const uint32_t* __restrict__ ovfIdx,
                       float* __restrict__ out)
{
    const int b = blockIdx.x >> 9;                 // 512 blocks/batch
    const int rowBase = (blockIdx.x & 511) * 16;   // 16 rows/block
    const int lane = threadIdx.x & 63;
    const int wave = threadIdx.x >> 6;             // 0..3
    const int sub = lane & 15;
    const int grp = lane >> 4;
    const int row = rowBase + wave * 4 + grp;

    // early independent loads (overlap the search)
    const uint32_t ovf = ovfCnt[b];
    const size_t arow = ((size_t)b * kNa + row) * kC;
    const float4 fa = *reinterpret_cast<const float4*>(feat_a + arow + sub * 4);

    const int* ca = coords_a + ((size_t)b * kNa + row) * 3;
    const int ax = ca[0], ay = ca[1], az = ca[2];
    const int aCell = (ax + kRad) * kGrid2 + (ay + kRad) * kGrid + (az + kRad);
    const int base = b * kGrid3 + aCell - kOff;

    uint32_t t0 = 0xFFFFFFFFu, t1 = t0, t2 = t0, t3 = t0, t4 = t0;
    int myCnt = 0;

    // ---- fused chunks 0 + 1: all 4 slot gathers in flight before inserts ----
    const uint2 eA = *reinterpret_cast<const uint2*>(kTab.e + sub * 2);
    const uint2 eB = *reinterpret_cast<const uint2*>(kTab.e + kChunkSz + sub * 2);
    const uint32_t dA0 = eA.x >> 18, dA1 = eA.y >> 18;
    const uint32_t dB0 = eB.x >> 18, dB1 = eB.y >> 18;
    const int cA0 = base + (int)(eA.x & 0x3FFFFu);
    const int cA1 = base + (int)(eA.y & 0x3FFFFu);
    const int cB0 = base + (int)(eB.x & 0x3FFFFu);
    const int cB1 = base + (int)(eB.y & 0x3FFFFu);
    uint2 sA0 = uint2{~0u, ~0u}, sA1 = sA0, sB0 = sA0, sB1 = sA0;
    if (dA0 <= (uint32_t)kDMax)
        sA0 = *reinterpret_cast<const uint2*>(slot16 + (size_t)cA0 * 4);
    if (dA1 <= (uint32_t)kDMax)
        sA1 = *reinterpret_cast<const uint2*>(slot16 + (size_t)cA1 * 4);
    if (dB0 <= (uint32_t)kDMax)
        sB0 = *reinterpret_cast<const uint2*>(slot16 + (size_t)cB0 * 4);
    if (dB1 <= (uint32_t)kDMax)
        sB1 = *reinterpret_cast<const uint2*>(slot16 + (size_t)cB1 * 4);

    const uint32_t kbA0 = dA0 << 13, kbA1 = dA1 << 13;
    const uint32_t kbB0 = dB0 << 13, kbB1 = dB1 << 13;

    // chunk 0 inserts
    UNPACK2_INS(sA0.x, kbA0, myCnt); UNPACK2_INS(sA0.y, kbA0, myCnt);
    UNPACK2_INS(sA1.x, kbA1, myCnt); UNPACK2_INS(sA1.y, kbA1, myCnt);
    const bool fullA0 = (sA0.y >> 16) != 0xFFFFu;   // slot3 valid => maybe >4 pts
    const bool fullA1 = (sA1.y >> 16) != 0xFFFFu;
    if (__any(fullA0 | fullA1)) {
        if (fullA0) {
            const uint32_t n = umin_(cnt[cA0], 8u);
            for (uint32_t m = 4; m < n; ++m)
                INSERT5(t0, t1, t2, t3, t4, kbA0 | slotHi[(size_t)cA0 * 4 + (m - 4u)]);
        }
        if (fullA1) {
            const uint32_t n = umin_(cnt[cA1], 8u);
            for (uint32_t m = 4; m < n; ++m)
                INSERT5(t0, t1, t2, t3, t4, kbA1 | slotHi[(size_t)cA1 * 4 + (m - 4u)]);
        }
    }

    int gs = groupSum16_(myCnt);
    bool doneG = (gs >= 5);                          // chunk0 boundary is canStop

    // chunk 1 inserts (data already fetched; skip if group satisfied)
    if (__any(!doneG)) {
        if (!doneG) {
            UNPACK2_INS(sB0.x, kbB0, myCnt); UNPACK2_INS(sB0.y, kbB0, myCnt);
            UNPACK2_INS(sB1.x, kbB1, myCnt); UNPACK2_INS(sB1.y, kbB1, myCnt);
            const bool fullB0 = (sB0.y >> 16) != 0xFFFFu;
            const bool fullB1 = (sB1.y >> 16) != 0xFFFFu;
            if (__any(fullB0 | fullB1)) {
                if (fullB0) {
                    const uint32_t n = umin_(cnt[cB0], 8u);
                    for (uint32_t m = 4; m < n; ++m)
                        INSERT5(t0, t1, t2, t3, t4, kbB0 | slotHi[(size_t)cB0 * 4 + (m - 4u)]);
                }
                if (fullB1) {
                    const uint32_t n = umin_(cnt[cB1], 8u);
                    for (uint32_t m = 4; m < n; ++m)
                        INSERT5(t0, t1, t2, t3, t4, kbB1 | slotHi[(size_t)cB1 * 4 + (m - 4u)]);
                }
            }
            gs = groupSum16_(myCnt);
            doneG = (gs >= 5);                       // chunk1 boundary is canStop
        } else {
            doneG = true;
        }
    }

    // ---- rare continuation: sequential shell loop from c = 2 ----
    if (__any(!doneG)) {
        bool done = doneG;
        for (int c = 2; c < kNChunks; ++c) {
            if (__all(done)) break;
            if (!done) {
                const uint2 ee = *reinterpret_cast<const uint2*>(
                                     kTab.e + c * kChunkSz + sub * 2);
                const uint32_t d20 = ee.x >> 18, d21 = ee.y >> 18;
                const int cell0 = base + (int)(ee.x & 0x3FFFFu);
                const int cell1 = base + (int)(ee.y & 0x3FFFFu);
                uint2 s0 = uint2{~0u, ~0u}, s1 = s0;
                if (d20 <= (uint32_t)kDMax)
                    s0 = *reinterpret_cast<const uint2*>(slot16 + (size_t)cell0 * 4);
                if (d21 <= (uint32_t)kDMax)
                    s1 = *reinterpret_cast<const uint2*>(slot16 + (size_t)cell1 * 4);
                const uint32_t kb0 = d20 << 13, kb1 = d21 << 13;
                UNPACK2_INS(s0.x, kb0, myCnt); UNPACK2_INS(s0.y, kb0, myCnt);
                UNPACK2_INS(s1.x, kb1, myCnt); UNPACK2_INS(s1.y, kb1, myCnt);
                const bool full0 = (s0.y >> 16) != 0xFFFFu;
                const bool full1 = (s1.y >> 16) != 0xFFFFu;
                if (__any(full0 | full1)) {
                    if (full0) {
                        const uint32_t n = umin_(cnt[cell0], 8u);
                        for (uint32_t m = 4; m < n; ++m)
                            INSERT5(t0, t1, t2, t3, t4,
                                    kb0 | slotHi[(size_t)cell0 * 4 + (m - 4u)]);
                    }
                    if (full1) {
                        const uint32_t n = umin_(cnt[cell1], 8u);
                        for (uint32_t m = 4; m < n; ++m)
                            INSERT5(t0, t1, t2, t3, t4,
                                    kb1 | slotHi[(size_t)cell1 * 4 + (m - 4u)]);
                    }
                }
                const bool canStop = (c < 64) ? (((kCS0 >> c) & 1ull) != 0)
                                              : (((kCS1 >> (c - 64)) & 1ull) != 0);
                if (canStop) {
                    if (groupSum16_(myCnt) >= 5) done = true;
                }
            }
        }
    }

    // ONE group merge per row
    groupMerge5_(t0, t1, t2, t3, t4);
    uint32_t g0 = t0, g1 = t1, g2 = t2, g3 = t3, g4 = t4;

    // ---- overflow fold + fallback (rare/cold) ----
    bool needFull = (ovf > (uint32_t)kOvfCap);
    if (!needFull && ovf > 0) {
        const int* cb = coords_b + (size_t)b * kNb * 3;
        uint32_t l0 = 0xFFFFFFFFu, l1 = l0, l2 = l0, l3 = l0, l4 = l0;
        for (uint32_t i = (uint32_t)sub; i < ovf; i += 16) {
            const uint32_t j = ovfIdx[b * kOvfCap + i];
            const int dx = ax - cb[3 * j + 0];
            const int dy = ay - cb[3 * j + 1];
            const int dz = az - cb[3 * j + 2];
            const uint32_t d2 = (uint32_t)(dx * dx + dy * dy + dz * dz);
            INSERT5(l0, l1, l2, l3, l4, (d2 << 13) | j);
        }
        groupMerge5_(l0, l1, l2, l3, l4);
        merge5_(g0, g1, g2, g3, g4, l0, l1, l2, l3, l4);
    }
    if (!needFull && (g4 >> 13) > (uint32_t)kDMax) needFull = true;
    if (__any(needFull)) {
        if (needFull) {                            // group-uniform predicate
            const int* cb = coords_b + (size_t)b * kNb * 3;
            uint32_t u0 = 0xFFFFFFFFu, u1 = u0, u2 = u0, u3 = u0, u4 = u0;
            for (int j = sub; j < kNb; j += 16) {
                const int dx = ax - cb[3 * j + 0];
                const int dy = ay - cb[3 * j + 1];
                const int dz = az - cb[3 * j + 2];
                const uint32_t d2 = (uint32_t)(dx * dx + dy * dy + dz * dz);
                INSERT5(u0, u1, u2, u3, u4, (d2 << 13) | (uint32_t)j);
            }
            groupMerge5_(u0, u1, u2, u3, u4);
            g0 = u0; g1 = u1; g2 = u2; g3 = u3; g4 = u4;
        }
    }

    // ---- weights + gather: lane = 4 channels (float4) ----
    const float* fb = feat_b + (size_t)b * kNb * kC;
    const uint32_t keys[5] = {g0, g1, g2, g3, g4};
    float4 acc = float4{0.f, 0.f, 0.f, 0.f};
    #pragma unroll
    for (int t = 0; t < 5; ++t) {
        const uint32_t key = keys[t];
        const int j = (int)(key & 8191u);
        const float dist = sqrtf((float)(key >> 13)) * (1.0f / 32.0f);
        const float w = 0.5f - fminf(dist, 0.5f);
        const float4 v = *reinterpret_cast<const float4*>(
                             fb + (size_t)j * kC + sub * 4);
        acc.x += w * v.x; acc.y += w * v.y; acc.z += w * v.z; acc.w += w * v.w;
    }

    const size_t orow = ((size_t)b * kNa + row) * (2 * kC);
    *reinterpret_cast<float4*>(out + orow + sub * 4) = fa;
    *reinterpret_cast<float4*>(out + orow + kC + sub * 4) = acc;
}

// ---------------- brute kernel (fallback if ws too small) ----------------

__global__ __launch_bounds__(512, 8)
void dist_match_brute(const int* __restrict__ coords_a,
                      const int* __restrict__ coords_b,
                      const float* __restrict__ feat_a,
                      const float* __restrict__ feat_b,
                      float* __restrict__ out)
{
    __shared__ int spack[kNb];
    const int b = blockIdx.x >> 10;
    const int rowBase = (blockIdx.x & 1023) * 8;
    const int tid = threadIdx.x;
    const int lane = tid & 63;
    const int wave = tid >> 6;

    const int* cb = coords_b + (size_t)b * kNb * 3;
    for (int j = tid; j < kNb; j += 512) {
        spack[j] = cb[3 * j + 0] | (cb[3 * j + 1] << 8) | (cb[3 * j + 2] << 16);
    }
    __syncthreads();

    const int row = rowBase + wave;
    const int* ca = coords_a + ((size_t)b * kNa + row) * 3;
    const int ax = ca[0], ay = ca[1], az = ca[2];
    const int a2 = ax * ax + ay * ay + az * az;
    const int paneg2 = ((-2 * ax) & 255) | (((-2 * ay) & 255) << 8)
                     | (((-2 * az) & 255) << 16);

    uint32_t t0 = 0xFFFFFFFFu, t1 = t0, t2 = t0, t3 = t0, t4 = t0;
    for (int k = 0; k < kNb / 256; ++k) {
        const int baseI = k * 256 + lane * 4;
        const int4 p4 = *reinterpret_cast<const int4*>(spack + baseI);
        const int ps[4] = {p4.x, p4.y, p4.z, p4.w};
        #pragma unroll
        for (int u = 0; u < 4; ++u) {
            const int p = ps[u];
            const int dot1 = __builtin_amdgcn_sdot4(paneg2, p, a2, false);
            const int d2 = __builtin_amdgcn_sdot4(p, p, dot1, false);
            const uint32_t key = ((uint32_t)d2 << 13) | (uint32_t)(baseI + u);
            INSERT5(t0, t1, t2, t3, t4, key);
        }
    }
    waveMerge5_(t0, t1, t2, t3, t4);
    const float* fb = feat_b + (size_t)b * kNb * kC;
    const uint32_t keys[5] = {t0, t1, t2, t3, t4};
    float acc = 0.0f;
    #pragma unroll
    for (int t = 0; t < 5; ++t) {
        const uint32_t key = keys[t];
        const int j = (int)(key & 8191u);
        const float dist = sqrtf((float)(key >> 13)) * (1.0f / 32.0f);
        const float w = 0.5f - fminf(dist, 0.5f);
        acc += w * fb[(size_t)j * kC + lane];
    }
    const size_t orow = ((size_t)b * kNa + row) * (2 * kC);
    out[orow + lane] = feat_a[((size_t)b * kNa + row) * kC + lane];
    out[orow + kC + lane] = acc;
}

extern "C" void kernel_launch(void* const* d_in, const int* in_sizes, int n_in,
                              void* d_out, int out_size, void* d_ws, size_t ws_size,
                              hipStream_t stream) {
    const int* coords_a = (const int*)d_in[0];
    const int* coords_b = (const int*)d_in[1];
    const float* feat_a = (const float*)d_in[2];
    const float* feat_b = (const float*)d_in[3];
    float* out = (float*)d_out;

    if (ws_size < kWsBytes) {
        dist_match_brute<<<kB * 1024, 512, 0, stream>>>(coords_a, coords_b,
                                                        feat_a, feat_b, out);
        return;
    }

    uint32_t* ws32 = (uint32_t*)d_ws;
    uint32_t* cnt    = ws32 + kCntOff;
    uint32_t* ovfCnt = ws32 + kOvfCntOff;
    uint32_t* ovfIdx = ws32 + kOvfIdxOff;
    uint16_t* slot16 = (uint16_t*)(ws32 + kSlot16Off);
    uint32_t* slotHi = ws32 + kSlotHiOff;

    k_clear<<<kClrBlocks, 256, 0, stream>>>((uint4*)d_ws);
    k_scatter<<<kB * kNb / 128, 128, 0, stream>>>(coords_b, cnt, slot16, slotHi,
                                                  ovfCnt, ovfIdx);
    dist_match_bucket<<<kB * 512, 256, 0, stream>>>(coords_a, coords_b,
                                                    feat_a, feat_b,
                                                    cnt, slot16, slotHi,
                                                    ovfCnt, ovfIdx, out);
}